// Round 8
// baseline (344.296 us; speedup 1.0000x reference)
//
#include <hip/hip_runtime.h>
#include <hip/hip_bf16.h>

#define Bb 8
#define Nn 1024
#define Hh 12
#define C3 2304
#define KK_E 0.1803368801f   // (1/8) * log2(e)
#define NQB 64               // queries per block (2 q-subtiles x 32; waves split KV)
#define KVBLK 64
#define NT 29
#define NQT (Nn / NQB)       // 16
#define NKT (Nn / KVBLK)     // 16
#define NBLK (Bb * Hh * NQT) // 1536
#define TILE_ELEMS 4096      // 64x64 bf16 tile

typedef short bf16x8 __attribute__((ext_vector_type(8)));
typedef float f32x16 __attribute__((ext_vector_type(16)));
typedef unsigned v2u __attribute__((ext_vector_type(2)));
typedef unsigned short u16t;

__device__ __forceinline__ float b2f(u16t v) {
    union { unsigned u; float f; } x; x.u = ((unsigned)v) << 16; return x.f;
}
__device__ __forceinline__ u16t f2b(float f) {
    union { float f; unsigned u; } x; x.f = f;
    unsigned r = x.u + 0x7fffu + ((x.u >> 16) & 1u);
    return (u16t)(r >> 16);
}
// single-instruction packed f32->bf16 (T12): dst.lo=bf16(a), dst.hi=bf16(b)
__device__ __forceinline__ unsigned pk2a(float a, float b) {
    unsigned r;
    asm("v_cvt_pk_bf16_f32 %0, %1, %2" : "=v"(r) : "v"(a), "v"(b));
    return r;
}

// ---------------- pass 1: fp32 -> bf16 in FRAG-LINEAR tile layout ----------------
// K tile (8KB): u16 idx = (key&31)*8 + (key>>5)*256 + ((d>>3)&1)*512 + (d>>4)*1024 + (d&7)
// V tile (8KB): u16 idx = (d&31)*8 + ((d>>5)&1)*256 + ((key>>3)&1)*512 + (key>>4)*1024 + (key&7)
// -> every MFMA fragment is 64 consecutive 16B chunks (one coalesced dwordx4 per lane)
__global__ __launch_bounds__(256) void preconv_kernel(
        const float* __restrict__ x, u16t* __restrict__ wsK, u16t* __restrict__ wsV) {
    __shared__ __align__(16) u16t Vt[TILE_ELEMS];
    const int bid = blockIdx.x;                 // ((b*H + h)*NKT + kt)
    const int kt = bid % NKT;
    const int h  = (bid / NKT) % Hh;
    const int b  = bid / (NKT * Hh);
    const int tid = threadIdx.x;
    const float* xb = x + (size_t)b * Nn * C3 + (size_t)kt * KVBLK * C3 + 768 + h * 64;
    u16t* Kdst = wsK + (size_t)bid * TILE_ELEMS;
    u16t* Vdst = wsV + (size_t)bid * TILE_ELEMS;

    #pragma unroll
    for (int rep = 0; rep < 4; ++rep) {
        int idx = tid + rep * 256;
        int m = idx >> 4;               // key 0..63
        int d0 = (idx & 15) * 4;        // d0 in {0,4,...,60}
        const float* src = &xb[(size_t)m * C3 + d0];
        float4 k4 = *(const float4*)src;
        uint2 kp;
        kp.x = pk2a(k4.x, k4.y);
        kp.y = pk2a(k4.z, k4.w);
        int ko = (m & 31) * 8 + (m >> 5) * 256 + ((d0 >> 3) & 1) * 512
               + (d0 >> 4) * 1024 + (d0 & 7);
        *(uint2*)&Kdst[ko] = kp;        // direct global, 8B aligned
        float4 v4 = *(const float4*)(src + 768);
        int vb = ((m >> 3) & 1) * 512 + (m >> 4) * 1024 + (m & 7);
        Vt[((d0 + 0) & 31) * 8 + (((d0 + 0) >> 5) & 1) * 256 + vb] = f2b(v4.x);
        Vt[((d0 + 1) & 31) * 8 + (((d0 + 1) >> 5) & 1) * 256 + vb] = f2b(v4.y);
        Vt[((d0 + 2) & 31) * 8 + (((d0 + 2) >> 5) & 1) * 256 + vb] = f2b(v4.z);
        Vt[((d0 + 3) & 31) * 8 + (((d0 + 3) >> 5) & 1) * 256 + vb] = f2b(v4.w);
    }
    __syncthreads();
    // tile already frag-linear in LDS: plain linear copy-out
    const float4* s = (const float4*)Vt;
    float4* d = (float4*)Vdst;
    d[tid] = s[tid];
    d[tid + 256] = s[tid + 256];
}

// ---------------- pass 2: attention — KV-split waves, zero main-loop barriers ----
// Waves: w&1 = q-subtile (32 rows), w>>1 = KV half (kt 0-7 / 8-15).
// LDS (24064 B -> 6 blocks/CU = 24 waves/CU):
//   [0,     14848) per-wave slabs 3712 B: wdiag bf16 [32][27] @0, qrel bf16 [32][29] @1792
//   [14848, 24064) merge buffer f32 [2][18][64] (two-phase of/sum merge)
__global__ __launch_bounds__(256, 5) void attn_kernel(
        const float* __restrict__ x,
        const float* __restrict__ tk,
        const float* __restrict__ tv,
        const u16t* __restrict__ wsK,
        const u16t* __restrict__ wsV,
        float* __restrict__ out) {
    __shared__ __align__(16) char smem[24064];

    const int tid = threadIdx.x;
    const int work = (blockIdx.x & 7) * (NBLK / 8) + (blockIdx.x >> 3);
    const int qt = work % NQT;
    const int h  = (work / NQT) % Hh;
    const int b  = work / (NQT * Hh);
    const int lane = tid & 63;
    const int w = tid >> 6;
    const int w01 = w & 1;               // q subtile
    const int wh  = w >> 1;              // kv half
    const int lq = lane & 31;
    const int hi = lane >> 5;
    const int q0 = qt * NQB;
    const int qw0 = q0 + w01 * 32;
    const int kt0 = wh * 8;

    char* slab   = smem + w * 3712;
    u16t* wdiagw = (u16t*)slab;              // [32][27] bf16
    u16t* qrelw  = (u16t*)(slab + 1792);     // [32][29] bf16
    float* mb    = (float*)(smem + 14848);   // [2][18][64] f32

    const u16t* Kbase = wsK + (size_t)((b * Hh + h) * NKT) * TILE_ELEMS;
    const u16t* Vbase = wsV + (size_t)((b * Hh + h) * NKT) * TILE_ELEMS;
    const int lofs = lq * 8 + hi * 512;      // per-lane u16 offset inside a tile

    // ---- first-tile K/V fragments straight into registers (coalesced dwordx4) ----
    bf16x8 kfr[2][4];   // [kb][slot]
    bf16x8 vfr[4][2];   // [kbj][db]
    {
        const u16t* Kt0 = Kbase + (size_t)kt0 * TILE_ELEMS + lofs;
        const u16t* Vt0 = Vbase + (size_t)kt0 * TILE_ELEMS + lofs;
        #pragma unroll
        for (int kb = 0; kb < 2; ++kb)
            #pragma unroll
            for (int slot = 0; slot < 4; ++slot)
                kfr[kb][slot] = *(const bf16x8*)&Kt0[kb * 256 + slot * 1024];
        #pragma unroll
        for (int kbj = 0; kbj < 4; ++kbj)
            #pragma unroll
            for (int db = 0; db < 2; ++db)
                vfr[kbj][db] = *(const bf16x8*)&Vt0[db * 256 + kbj * 1024];
    }

    // ---- Q fragments direct from global, pre-scaled by KK_E ----
    const float* xq = x + (size_t)b * Nn * C3 + (size_t)(qw0 + lq) * C3 + h * 64;
    bf16x8 qB[4];
    #pragma unroll
    for (int slot = 0; slot < 4; ++slot) {
        float4 a4 = *(const float4*)&xq[slot * 16 + hi * 8];
        float4 b4 = *(const float4*)&xq[slot * 16 + hi * 8 + 4];
        union { bf16x8 v; unsigned u[4]; } pk;
        pk.u[0] = pk2a(a4.x * KK_E, a4.y * KK_E);
        pk.u[1] = pk2a(a4.z * KK_E, a4.w * KK_E);
        pk.u[2] = pk2a(b4.x * KK_E, b4.y * KK_E);
        pk.u[3] = pk2a(b4.z * KK_E, b4.w * KK_E);
        qB[slot] = pk.v;
    }

    // ---- qrel[q][t] = (KK_E*Q[q,:]).tk[t,:] via 4 MFMAs: D[q=crow(reg,hi)][t=lq] ----
    {
        const int tc = lq > 28 ? 28 : lq;
        f32x16 qr = {};
        #pragma unroll
        for (int slot = 0; slot < 4; ++slot) {
            const float* tp = &tk[tc * 64 + slot * 16 + hi * 8];
            float4 a4 = *(const float4*)tp;
            float4 b4 = *(const float4*)(tp + 4);
            union { bf16x8 v; unsigned u[4]; } pk;
            pk.u[0] = pk2a(a4.x, a4.y); pk.u[1] = pk2a(a4.z, a4.w);
            pk.u[2] = pk2a(b4.x, b4.y); pk.u[3] = pk2a(b4.z, b4.w);
            qr = __builtin_amdgcn_mfma_f32_32x32x16_bf16(qB[slot], pk.v, qr, 0, 0, 0);
        }
        if (lq <= 28) {
            #pragma unroll
            for (int reg = 0; reg < 16; ++reg) {
                int qrow = (reg & 3) + 8 * (reg >> 2) + 4 * hi;
                qrelw[qrow * NT + lq] = f2b(qr[reg]);
            }
        }
    }
    // zero wdiag (wave-private; same-wave LDS ordering)
    for (int i = lane; i < 432; i += 64) ((unsigned*)wdiagw)[i] = 0u;

    const float qb0  = b2f(qrelw[lq * NT + 0]);    // already scaled
    const float qb28 = b2f(qrelw[lq * NT + 28]);

    f32x16 of[2] = {};
    float lowA = 0.f, highA = 0.f;

    for (int kt = kt0; kt < kt0 + 8; ++kt) {
        const int key00 = kt * KVBLK;
        const bool more = (kt + 1 < kt0 + 8);
        const u16t* Ktn = Kbase + (size_t)(kt + 1) * TILE_ELEMS + lofs;
        const u16t* Vtn = Vbase + (size_t)(kt + 1) * TILE_ELEMS + lofs;

        #pragma unroll
        for (int kb = 0; kb < 2; ++kb) {
            const int kbase = key00 + kb * 32;
            const bool flo = (kbase + 31 - qw0 <= -14);
            const bool fhi = (kbase - (qw0 + 31) >= 14);
            const float binit = flo ? qb0 : (fhi ? qb28 : 0.f);
            f32x16 s;
            #pragma unroll
            for (int r = 0; r < 16; ++r) s[r] = binit;   // bias folded into C-init
            __builtin_amdgcn_s_setprio(1);
            #pragma unroll
            for (int slot = 0; slot < 4; ++slot)
                s = __builtin_amdgcn_mfma_f32_32x32x16_bf16(kfr[kb][slot], qB[slot], s, 0, 0, 0);
            __builtin_amdgcn_s_setprio(0);
            // phase-shifted reload: K(kt+1) for this kb, right after last use
            if (more) {
                #pragma unroll
                for (int slot = 0; slot < 4; ++slot)
                    kfr[kb][slot] = *(const bf16x8*)&Ktn[kb * 256 + slot * 1024];
            }
            // lane holds S^T[key = kbase+(r&3)+8*(r>>2)+4*hi][q = qw0+lq] (+bias)
            float e[16];
            if (flo || fhi) {
                #pragma unroll
                for (int r = 0; r < 16; ++r) e[r] = __builtin_amdgcn_exp2f(s[r]);
                float a0 = (e[0]+e[1]) + (e[2]+e[3]);
                float a1 = (e[4]+e[5]) + (e[6]+e[7]);
                float a2 = (e[8]+e[9]) + (e[10]+e[11]);
                float a3 = (e[12]+e[13]) + (e[14]+e[15]);
                float at = (a0+a1) + (a2+a3);
                if (flo) lowA += at; else highA += at;
            } else {
                const int qg = qw0 + lq;
                #pragma unroll
                for (int r = 0; r < 16; ++r) {
                    int key = kbase + (r & 3) + 8 * (r >> 2) + 4 * hi;
                    int delta = key - qg;
                    int t = delta + 14;
                    t = t < 0 ? 0 : (t > 28 ? 28 : t);
                    e[r] = __builtin_amdgcn_exp2f(s[r] + b2f(qrelw[lq * NT + t]));
                    if (delta <= -14)      lowA += e[r];
                    else if (delta >= 14)  highA += e[r];
                    else                   wdiagw[lq * 27 + delta + 13] = f2b(e[r]);
                }
            }
            // T12: cvt_pk + permlane32_swap -> PV B-frags in registers
            unsigned A0 = pk2a(e[0],  e[1]),  B0 = pk2a(e[2],  e[3]);
            unsigned C0 = pk2a(e[4],  e[5]),  D0 = pk2a(e[6],  e[7]);
            unsigned A1 = pk2a(e[8],  e[9]),  B1 = pk2a(e[10], e[11]);
            unsigned C1 = pk2a(e[12], e[13]), D1 = pk2a(e[14], e[15]);
            v2u r0 = __builtin_amdgcn_permlane32_swap(A0, C0, false, false);
            v2u r1 = __builtin_amdgcn_permlane32_swap(B0, D0, false, false);
            v2u r2 = __builtin_amdgcn_permlane32_swap(A1, C1, false, false);
            v2u r3 = __builtin_amdgcn_permlane32_swap(B1, D1, false, false);
            union { bf16x8 v; unsigned u[4]; } pf0, pf1;
            pf0.u[0] = r0[0]; pf0.u[1] = r1[0]; pf0.u[2] = r0[1]; pf0.u[3] = r1[1];
            pf1.u[0] = r2[0]; pf1.u[1] = r3[0]; pf1.u[2] = r2[1]; pf1.u[3] = r3[1];
            __builtin_amdgcn_s_setprio(1);
            #pragma unroll
            for (int db = 0; db < 2; ++db) {
                of[db] = __builtin_amdgcn_mfma_f32_32x32x16_bf16(vfr[kb*2+0][db], pf0.v, of[db], 0, 0, 0);
                of[db] = __builtin_amdgcn_mfma_f32_32x32x16_bf16(vfr[kb*2+1][db], pf1.v, of[db], 0, 0, 0);
            }
            __builtin_amdgcn_s_setprio(0);
            // phase-shifted reload: V(kt+1) for this kb's two key sub-groups
            if (more) {
                #pragma unroll
                for (int j = 0; j < 2; ++j)
                    #pragma unroll
                    for (int db = 0; db < 2; ++db)
                        vfr[kb*2+j][db] = *(const bf16x8*)&Vtn[db * 256 + (kb*2+j) * 1024];
            }
        }
    }

    // ---- two-phase KV-half merge (upper waves wh==1 -> lower waves wh==0) ----
    {
        float* mbw = mb + w01 * 18 * 64;
        if (wh == 1) {
            #pragma unroll
            for (int r = 0; r < 16; ++r) mbw[r * 64 + lane] = of[0][r];
            mbw[16 * 64 + lane] = lowA;
            mbw[17 * 64 + lane] = highA;
        }
        __syncthreads();
        if (wh == 0) {
            #pragma unroll
            for (int r = 0; r < 16; ++r) of[0][r] += mbw[r * 64 + lane];
            lowA  += mbw[16 * 64 + lane];
            highA += mbw[17 * 64 + lane];
        }
        __syncthreads();
        if (wh == 1) {
            #pragma unroll
            for (int r = 0; r < 16; ++r) mbw[r * 64 + lane] = of[1][r];
        }
        __syncthreads();
        if (wh == 1) return;   // upper waves done; no further barriers below
        #pragma unroll
        for (int r = 0; r < 16; ++r) of[1][r] += mbw[r * 64 + lane];
    }

    // ---- lower waves only: finish sums, out2, epilogue ----
    lowA  += __shfl_xor(lowA, 32, 64);
    highA += __shfl_xor(highA, 32, 64);
    float wsum = lowA + highA;

    const u16t* wdiagup = (const u16t*)(smem + (w + 2) * 3712);   // partner slab

    float acc[2][16];
    #pragma unroll
    for (int db = 0; db < 2; ++db)
        #pragma unroll
        for (int rq = 0; rq < 4; ++rq) {
            int d0 = db * 32 + rq * 8 + hi * 4;
            float4 ta = *(const float4*)&tv[d0];
            float4 tb = *(const float4*)&tv[28 * 64 + d0];
            acc[db][rq * 4 + 0] = lowA * ta.x + highA * tb.x;
            acc[db][rq * 4 + 1] = lowA * ta.y + highA * tb.y;
            acc[db][rq * 4 + 2] = lowA * ta.z + highA * tb.z;
            acc[db][rq * 4 + 3] = lowA * ta.w + highA * tb.w;
        }
    for (int t = 1; t <= 27; ++t) {
        float wv = b2f(wdiagw[lq * 27 + t - 1]) + b2f(wdiagup[lq * 27 + t - 1]);
        wsum += wv;
        #pragma unroll
        for (int db = 0; db < 2; ++db)
            #pragma unroll
            for (int rq = 0; rq < 4; ++rq) {
                int d0 = db * 32 + rq * 8 + hi * 4;
                float4 tr = *(const float4*)&tv[t * 64 + d0];
                acc[db][rq * 4 + 0] = fmaf(wv, tr.x, acc[db][rq * 4 + 0]);
                acc[db][rq * 4 + 1] = fmaf(wv, tr.y, acc[db][rq * 4 + 1]);
                acc[db][rq * 4 + 2] = fmaf(wv, tr.z, acc[db][rq * 4 + 2]);
                acc[db][rq * 4 + 3] = fmaf(wv, tr.w, acc[db][rq * 4 + 3]);
            }
    }
    const float linv = __builtin_amdgcn_rcpf(wsum);

    {
        float* orow = &out[((size_t)b * Nn + qw0 + lq) * 768 + h * 64];
        #pragma unroll
        for (int db = 0; db < 2; ++db)
            #pragma unroll
            for (int rq = 0; rq < 4; ++rq) {
                int d0 = db * 32 + rq * 8 + hi * 4;
                float4 o4;
                o4.x = (of[db][rq * 4 + 0] + acc[db][rq * 4 + 0]) * linv;
                o4.y = (of[db][rq * 4 + 1] + acc[db][rq * 4 + 1]) * linv;
                o4.z = (of[db][rq * 4 + 2] + acc[db][rq * 4 + 2]) * linv;
                o4.w = (of[db][rq * 4 + 3] + acc[db][rq * 4 + 3]) * linv;
                *(float4*)&orow[d0] = o4;
            }
    }
}

extern "C" void kernel_launch(void* const* d_in, const int* in_sizes, int n_in,
                              void* d_out, int out_size, void* d_ws, size_t ws_size,
                              hipStream_t stream) {
    const float* x  = (const float*)d_in[0];
    const float* tk = (const float*)d_in[1];
    const float* tv = (const float*)d_in[2];
    float* out = (float*)d_out;
    u16t* wsK = (u16t*)d_ws;
    u16t* wsV = wsK + (size_t)Bb * Hh * NKT * TILE_ELEMS;
    preconv_kernel<<<dim3(Bb * Hh * NKT), dim3(256), 0, stream>>>(x, wsK, wsV);
    attn_kernel<<<dim3(NBLK), dim3(256), 0, stream>>>(x, tk, tv, wsK, wsV, out);
}

// Round 9
// 190.777 us; speedup vs baseline: 1.8047x; 1.8047x over previous
//
#include <hip/hip_runtime.h>
#include <hip/hip_bf16.h>

#define Bb 8
#define Nn 1024
#define Hh 12
#define C3 2304
#define KK_E 0.1803368801f   // (1/8) * log2(e)
#define NQB 64               // queries per block (2 q-subtiles x 32; waves split KV)
#define KVBLK 64
#define NT 29
#define NQT (Nn / NQB)       // 16
#define NKT (Nn / KVBLK)     // 16
#define NBLK (Bb * Hh * NQT) // 1536
#define TILE_ELEMS 4096      // 64x64 bf16 tile

typedef short bf16x8 __attribute__((ext_vector_type(8)));
typedef float f32x16 __attribute__((ext_vector_type(16)));
typedef unsigned v2u __attribute__((ext_vector_type(2)));
typedef unsigned short u16t;

__device__ __forceinline__ float b2f(u16t v) {
    union { unsigned u; float f; } x; x.u = ((unsigned)v) << 16; return x.f;
}
__device__ __forceinline__ u16t f2b(float f) {
    union { float f; unsigned u; } x; x.f = f;
    unsigned r = x.u + 0x7fffu + ((x.u >> 16) & 1u);
    return (u16t)(r >> 16);
}
// single-instruction packed f32->bf16 (T12): dst.lo=bf16(a), dst.hi=bf16(b)
__device__ __forceinline__ unsigned pk2a(float a, float b) {
    unsigned r;
    asm("v_cvt_pk_bf16_f32 %0, %1, %2" : "=v"(r) : "v"(a), "v"(b));
    return r;
}

// ---------------- pass 1: fp32 -> bf16 in FRAG-LINEAR tile layout ----------------
// K tile (8KB): u16 idx = (key&31)*8 + (key>>5)*256 + ((d>>3)&1)*512 + (d>>4)*1024 + (d&7)
// V tile (8KB): u16 idx = (d&31)*8 + ((d>>5)&1)*256 + ((key>>3)&1)*512 + (key>>4)*1024 + (key&7)
// -> every MFMA fragment is 64 consecutive 16B chunks (one coalesced dwordx4 per lane)
__global__ __launch_bounds__(256) void preconv_kernel(
        const float* __restrict__ x, u16t* __restrict__ wsK, u16t* __restrict__ wsV) {
    __shared__ __align__(16) u16t Vt[TILE_ELEMS];
    const int bid = blockIdx.x;                 // ((b*H + h)*NKT + kt)
    const int kt = bid % NKT;
    const int h  = (bid / NKT) % Hh;
    const int b  = bid / (NKT * Hh);
    const int tid = threadIdx.x;
    const float* xb = x + (size_t)b * Nn * C3 + (size_t)kt * KVBLK * C3 + 768 + h * 64;
    u16t* Kdst = wsK + (size_t)bid * TILE_ELEMS;
    u16t* Vdst = wsV + (size_t)bid * TILE_ELEMS;

    #pragma unroll
    for (int rep = 0; rep < 4; ++rep) {
        int idx = tid + rep * 256;
        int m = idx >> 4;               // key 0..63
        int d0 = (idx & 15) * 4;        // d0 in {0,4,...,60}
        const float* src = &xb[(size_t)m * C3 + d0];
        float4 k4 = *(const float4*)src;
        uint2 kp;
        kp.x = pk2a(k4.x, k4.y);
        kp.y = pk2a(k4.z, k4.w);
        int ko = (m & 31) * 8 + (m >> 5) * 256 + ((d0 >> 3) & 1) * 512
               + (d0 >> 4) * 1024 + (d0 & 7);
        *(uint2*)&Kdst[ko] = kp;        // direct global, 8B aligned
        float4 v4 = *(const float4*)(src + 768);
        int vb = ((m >> 3) & 1) * 512 + (m >> 4) * 1024 + (m & 7);
        Vt[((d0 + 0) & 31) * 8 + (((d0 + 0) >> 5) & 1) * 256 + vb] = f2b(v4.x);
        Vt[((d0 + 1) & 31) * 8 + (((d0 + 1) >> 5) & 1) * 256 + vb] = f2b(v4.y);
        Vt[((d0 + 2) & 31) * 8 + (((d0 + 2) >> 5) & 1) * 256 + vb] = f2b(v4.z);
        Vt[((d0 + 3) & 31) * 8 + (((d0 + 3) >> 5) & 1) * 256 + vb] = f2b(v4.w);
    }
    __syncthreads();
    // tile already frag-linear in LDS: plain linear copy-out
    const float4* s = (const float4*)Vt;
    float4* d = (float4*)Vdst;
    d[tid] = s[tid];
    d[tid + 256] = s[tid + 256];
}

// ---------------- pass 2: attention — KV-split waves, zero main-loop barriers ----
// Waves: w&1 = q-subtile (32 rows), w>>1 = KV half (kt 0-7 / 8-15).
// LDS (24064 B -> up to 6 blocks/CU):
//   [0,     14848) per-wave slabs 3712 B: wdiag bf16 [32][27] @0, qrel bf16 [32][29] @1792
//   [14848, 24064) merge buffer f32 [2][18][64] (two-phase of/sum merge)
// __launch_bounds__(256,4): VGPR cap 128 — loop needs ~90-110 live; (256,5)'s cap
// of ~102 caused wholesale f32x16 spill (r8: VGPR 48, 876MB scratch writes).
__global__ __launch_bounds__(256, 4) void attn_kernel(
        const float* __restrict__ x,
        const float* __restrict__ tk,
        const float* __restrict__ tv,
        const u16t* __restrict__ wsK,
        const u16t* __restrict__ wsV,
        float* __restrict__ out) {
    __shared__ __align__(16) char smem[24064];

    const int tid = threadIdx.x;
    const int work = (blockIdx.x & 7) * (NBLK / 8) + (blockIdx.x >> 3);
    const int qt = work % NQT;
    const int h  = (work / NQT) % Hh;
    const int b  = work / (NQT * Hh);
    const int lane = tid & 63;
    const int w = tid >> 6;
    const int w01 = w & 1;               // q subtile
    const int wh  = w >> 1;              // kv half
    const int lq = lane & 31;
    const int hi = lane >> 5;
    const int q0 = qt * NQB;
    const int qw0 = q0 + w01 * 32;
    const int kt0 = wh * 8;

    char* slab   = smem + w * 3712;
    u16t* wdiagw = (u16t*)slab;              // [32][27] bf16
    u16t* qrelw  = (u16t*)(slab + 1792);     // [32][29] bf16
    float* mb    = (float*)(smem + 14848);   // [2][18][64] f32

    const u16t* Kbase = wsK + (size_t)((b * Hh + h) * NKT) * TILE_ELEMS;
    const u16t* Vbase = wsV + (size_t)((b * Hh + h) * NKT) * TILE_ELEMS;
    const int lofs = lq * 8 + hi * 512;      // per-lane u16 offset inside a tile

    // ---- first-tile K/V fragments straight into registers (coalesced dwordx4) ----
    bf16x8 kfr[2][4];   // [kb][slot]
    bf16x8 vfr[4][2];   // [kbj][db]
    {
        const u16t* Kt0 = Kbase + (size_t)kt0 * TILE_ELEMS + lofs;
        const u16t* Vt0 = Vbase + (size_t)kt0 * TILE_ELEMS + lofs;
        #pragma unroll
        for (int kb = 0; kb < 2; ++kb)
            #pragma unroll
            for (int slot = 0; slot < 4; ++slot)
                kfr[kb][slot] = *(const bf16x8*)&Kt0[kb * 256 + slot * 1024];
        #pragma unroll
        for (int kbj = 0; kbj < 4; ++kbj)
            #pragma unroll
            for (int db = 0; db < 2; ++db)
                vfr[kbj][db] = *(const bf16x8*)&Vt0[db * 256 + kbj * 1024];
    }

    // ---- Q fragments direct from global, pre-scaled by KK_E ----
    const float* xq = x + (size_t)b * Nn * C3 + (size_t)(qw0 + lq) * C3 + h * 64;
    bf16x8 qB[4];
    #pragma unroll
    for (int slot = 0; slot < 4; ++slot) {
        float4 a4 = *(const float4*)&xq[slot * 16 + hi * 8];
        float4 b4 = *(const float4*)&xq[slot * 16 + hi * 8 + 4];
        union { bf16x8 v; unsigned u[4]; } pk;
        pk.u[0] = pk2a(a4.x * KK_E, a4.y * KK_E);
        pk.u[1] = pk2a(a4.z * KK_E, a4.w * KK_E);
        pk.u[2] = pk2a(b4.x * KK_E, b4.y * KK_E);
        pk.u[3] = pk2a(b4.z * KK_E, b4.w * KK_E);
        qB[slot] = pk.v;
    }

    // ---- qrel[q][t] = (KK_E*Q[q,:]).tk[t,:] via 4 MFMAs: D[q=crow(reg,hi)][t=lq] ----
    {
        const int tc = lq > 28 ? 28 : lq;
        f32x16 qr = {};
        #pragma unroll
        for (int slot = 0; slot < 4; ++slot) {
            const float* tp = &tk[tc * 64 + slot * 16 + hi * 8];
            float4 a4 = *(const float4*)tp;
            float4 b4 = *(const float4*)(tp + 4);
            union { bf16x8 v; unsigned u[4]; } pk;
            pk.u[0] = pk2a(a4.x, a4.y); pk.u[1] = pk2a(a4.z, a4.w);
            pk.u[2] = pk2a(b4.x, b4.y); pk.u[3] = pk2a(b4.z, b4.w);
            qr = __builtin_amdgcn_mfma_f32_32x32x16_bf16(qB[slot], pk.v, qr, 0, 0, 0);
        }
        if (lq <= 28) {
            #pragma unroll
            for (int reg = 0; reg < 16; ++reg) {
                int qrow = (reg & 3) + 8 * (reg >> 2) + 4 * hi;
                qrelw[qrow * NT + lq] = f2b(qr[reg]);
            }
        }
    }
    // zero wdiag (wave-private; same-wave LDS ordering)
    for (int i = lane; i < 432; i += 64) ((unsigned*)wdiagw)[i] = 0u;

    const float qb0  = b2f(qrelw[lq * NT + 0]);    // already scaled
    const float qb28 = b2f(qrelw[lq * NT + 28]);

    f32x16 of[2] = {};
    float lowA = 0.f, highA = 0.f;

    for (int kt = kt0; kt < kt0 + 8; ++kt) {
        const int key00 = kt * KVBLK;
        const bool more = (kt + 1 < kt0 + 8);
        const u16t* Ktn = Kbase + (size_t)(kt + 1) * TILE_ELEMS + lofs;
        const u16t* Vtn = Vbase + (size_t)(kt + 1) * TILE_ELEMS + lofs;

        #pragma unroll
        for (int kb = 0; kb < 2; ++kb) {
            const int kbase = key00 + kb * 32;
            const bool flo = (kbase + 31 - qw0 <= -14);
            const bool fhi = (kbase - (qw0 + 31) >= 14);
            const float binit = flo ? qb0 : (fhi ? qb28 : 0.f);
            f32x16 s;
            #pragma unroll
            for (int r = 0; r < 16; ++r) s[r] = binit;   // bias folded into C-init
            __builtin_amdgcn_s_setprio(1);
            #pragma unroll
            for (int slot = 0; slot < 4; ++slot)
                s = __builtin_amdgcn_mfma_f32_32x32x16_bf16(kfr[kb][slot], qB[slot], s, 0, 0, 0);
            __builtin_amdgcn_s_setprio(0);
            // phase-shifted reload: K(kt+1) for this kb, right after last use
            if (more) {
                #pragma unroll
                for (int slot = 0; slot < 4; ++slot)
                    kfr[kb][slot] = *(const bf16x8*)&Ktn[kb * 256 + slot * 1024];
            }
            // lane holds S^T[key = kbase+(r&3)+8*(r>>2)+4*hi][q = qw0+lq] (+bias)
            float e[16];
            if (flo || fhi) {
                #pragma unroll
                for (int r = 0; r < 16; ++r) e[r] = __builtin_amdgcn_exp2f(s[r]);
                float a0 = (e[0]+e[1]) + (e[2]+e[3]);
                float a1 = (e[4]+e[5]) + (e[6]+e[7]);
                float a2 = (e[8]+e[9]) + (e[10]+e[11]);
                float a3 = (e[12]+e[13]) + (e[14]+e[15]);
                float at = (a0+a1) + (a2+a3);
                if (flo) lowA += at; else highA += at;
            } else {
                const int qg = qw0 + lq;
                #pragma unroll
                for (int r = 0; r < 16; ++r) {
                    int key = kbase + (r & 3) + 8 * (r >> 2) + 4 * hi;
                    int delta = key - qg;
                    int t = delta + 14;
                    t = t < 0 ? 0 : (t > 28 ? 28 : t);
                    e[r] = __builtin_amdgcn_exp2f(s[r] + b2f(qrelw[lq * NT + t]));
                    if (delta <= -14)      lowA += e[r];
                    else if (delta >= 14)  highA += e[r];
                    else                   wdiagw[lq * 27 + delta + 13] = f2b(e[r]);
                }
            }
            // T12: cvt_pk + permlane32_swap -> PV B-frags in registers
            unsigned A0 = pk2a(e[0],  e[1]),  B0 = pk2a(e[2],  e[3]);
            unsigned C0 = pk2a(e[4],  e[5]),  D0 = pk2a(e[6],  e[7]);
            unsigned A1 = pk2a(e[8],  e[9]),  B1 = pk2a(e[10], e[11]);
            unsigned C1 = pk2a(e[12], e[13]), D1 = pk2a(e[14], e[15]);
            v2u r0 = __builtin_amdgcn_permlane32_swap(A0, C0, false, false);
            v2u r1 = __builtin_amdgcn_permlane32_swap(B0, D0, false, false);
            v2u r2 = __builtin_amdgcn_permlane32_swap(A1, C1, false, false);
            v2u r3 = __builtin_amdgcn_permlane32_swap(B1, D1, false, false);
            union { bf16x8 v; unsigned u[4]; } pf0, pf1;
            pf0.u[0] = r0[0]; pf0.u[1] = r1[0]; pf0.u[2] = r0[1]; pf0.u[3] = r1[1];
            pf1.u[0] = r2[0]; pf1.u[1] = r3[0]; pf1.u[2] = r2[1]; pf1.u[3] = r3[1];
            __builtin_amdgcn_s_setprio(1);
            #pragma unroll
            for (int db = 0; db < 2; ++db) {
                of[db] = __builtin_amdgcn_mfma_f32_32x32x16_bf16(vfr[kb*2+0][db], pf0.v, of[db], 0, 0, 0);
                of[db] = __builtin_amdgcn_mfma_f32_32x32x16_bf16(vfr[kb*2+1][db], pf1.v, of[db], 0, 0, 0);
            }
            __builtin_amdgcn_s_setprio(0);
            // phase-shifted reload: V(kt+1) for this kb's two key sub-groups
            if (more) {
                #pragma unroll
                for (int j = 0; j < 2; ++j)
                    #pragma unroll
                    for (int db = 0; db < 2; ++db)
                        vfr[kb*2+j][db] = *(const bf16x8*)&Vtn[db * 256 + (kb*2+j) * 1024];
            }
        }
    }

    // ---- two-phase KV-half merge (upper waves wh==1 -> lower waves wh==0) ----
    {
        float* mbw = mb + w01 * 18 * 64;
        if (wh == 1) {
            #pragma unroll
            for (int r = 0; r < 16; ++r) mbw[r * 64 + lane] = of[0][r];
            mbw[16 * 64 + lane] = lowA;
            mbw[17 * 64 + lane] = highA;
        }
        __syncthreads();
        if (wh == 0) {
            #pragma unroll
            for (int r = 0; r < 16; ++r) of[0][r] += mbw[r * 64 + lane];
            lowA  += mbw[16 * 64 + lane];
            highA += mbw[17 * 64 + lane];
        }
        __syncthreads();
        if (wh == 1) {
            #pragma unroll
            for (int r = 0; r < 16; ++r) mbw[r * 64 + lane] = of[1][r];
        }
        __syncthreads();
        if (wh == 1) return;   // upper waves done; no further barriers below
        #pragma unroll
        for (int r = 0; r < 16; ++r) of[1][r] += mbw[r * 64 + lane];
    }

    // ---- lower waves only: finish sums, out2, epilogue ----
    lowA  += __shfl_xor(lowA, 32, 64);
    highA += __shfl_xor(highA, 32, 64);
    float wsum = lowA + highA;

    const u16t* wdiagup = (const u16t*)(smem + (w + 2) * 3712);   // partner slab

    float acc[2][16];
    #pragma unroll
    for (int db = 0; db < 2; ++db)
        #pragma unroll
        for (int rq = 0; rq < 4; ++rq) {
            int d0 = db * 32 + rq * 8 + hi * 4;
            float4 ta = *(const float4*)&tv[d0];
            float4 tb = *(const float4*)&tv[28 * 64 + d0];
            acc[db][rq * 4 + 0] = lowA * ta.x + highA * tb.x;
            acc[db][rq * 4 + 1] = lowA * ta.y + highA * tb.y;
            acc[db][rq * 4 + 2] = lowA * ta.z + highA * tb.z;
            acc[db][rq * 4 + 3] = lowA * ta.w + highA * tb.w;
        }
    for (int t = 1; t <= 27; ++t) {
        float wv = b2f(wdiagw[lq * 27 + t - 1]) + b2f(wdiagup[lq * 27 + t - 1]);
        wsum += wv;
        #pragma unroll
        for (int db = 0; db < 2; ++db)
            #pragma unroll
            for (int rq = 0; rq < 4; ++rq) {
                int d0 = db * 32 + rq * 8 + hi * 4;
                float4 tr = *(const float4*)&tv[t * 64 + d0];
                acc[db][rq * 4 + 0] = fmaf(wv, tr.x, acc[db][rq * 4 + 0]);
                acc[db][rq * 4 + 1] = fmaf(wv, tr.y, acc[db][rq * 4 + 1]);
                acc[db][rq * 4 + 2] = fmaf(wv, tr.z, acc[db][rq * 4 + 2]);
                acc[db][rq * 4 + 3] = fmaf(wv, tr.w, acc[db][rq * 4 + 3]);
            }
    }
    const float linv = __builtin_amdgcn_rcpf(wsum);

    {
        float* orow = &out[((size_t)b * Nn + qw0 + lq) * 768 + h * 64];
        #pragma unroll
        for (int db = 0; db < 2; ++db)
            #pragma unroll
            for (int rq = 0; rq < 4; ++rq) {
                int d0 = db * 32 + rq * 8 + hi * 4;
                float4 o4;
                o4.x = (of[db][rq * 4 + 0] + acc[db][rq * 4 + 0]) * linv;
                o4.y = (of[db][rq * 4 + 1] + acc[db][rq * 4 + 1]) * linv;
                o4.z = (of[db][rq * 4 + 2] + acc[db][rq * 4 + 2]) * linv;
                o4.w = (of[db][rq * 4 + 3] + acc[db][rq * 4 + 3]) * linv;
                *(float4*)&orow[d0] = o4;
            }
    }
}

extern "C" void kernel_launch(void* const* d_in, const int* in_sizes, int n_in,
                              void* d_out, int out_size, void* d_ws, size_t ws_size,
                              hipStream_t stream) {
    const float* x  = (const float*)d_in[0];
    const float* tk = (const float*)d_in[1];
    const float* tv = (const float*)d_in[2];
    float* out = (float*)d_out;
    u16t* wsK = (u16t*)d_ws;
    u16t* wsV = wsK + (size_t)Bb * Hh * NKT * TILE_ELEMS;
    preconv_kernel<<<dim3(Bb * Hh * NKT), dim3(256), 0, stream>>>(x, wsK, wsV);
    attn_kernel<<<dim3(NBLK), dim3(256), 0, stream>>>(x, tk, tv, wsK, wsV, out);
}

// Round 10
// 88.053 us; speedup vs baseline: 3.9101x; 2.1666x over previous
//
#include <hip/hip_runtime.h>
#include <hip/hip_bf16.h>

#define Bb 8
#define Nn 1024
#define Hh 12
#define C3 2304
#define KK_E 0.1803368801f   // (1/8) * log2(e)
#define KVBLK 64
#define NT 29
#define NQC 32               // 32-q chunks per sequence: Nn/32
#define NKT (Nn / KVBLK)     // 16
#define NBLK (Bb * Hh * NQC) // 3072 blocks (2 waves each = kv halves)
#define TILE_ELEMS 4096      // 64x64 bf16 tile

typedef short bf16x8 __attribute__((ext_vector_type(8)));
typedef float f32x16 __attribute__((ext_vector_type(16)));
typedef unsigned v2u __attribute__((ext_vector_type(2)));
typedef unsigned short u16t;

__device__ __forceinline__ float b2f(u16t v) {
    union { unsigned u; float f; } x; x.u = ((unsigned)v) << 16; return x.f;
}
__device__ __forceinline__ u16t f2b(float f) {
    union { float f; unsigned u; } x; x.f = f;
    unsigned r = x.u + 0x7fffu + ((x.u >> 16) & 1u);
    return (u16t)(r >> 16);
}
// single-instruction packed f32->bf16 (T12): dst.lo=bf16(a), dst.hi=bf16(b)
__device__ __forceinline__ unsigned pk2a(float a, float b) {
    unsigned r;
    asm("v_cvt_pk_bf16_f32 %0, %1, %2" : "=v"(r) : "v"(a), "v"(b));
    return r;
}

// ---------------- pass 1: fp32 -> bf16 in FRAG-LINEAR tile layout ----------------
// K tile (8KB): u16 idx = (key&31)*8 + (key>>5)*256 + ((d>>3)&1)*512 + (d>>4)*1024 + (d&7)
// V tile (8KB): u16 idx = (d&31)*8 + ((d>>5)&1)*256 + ((key>>3)&1)*512 + (key>>4)*1024 + (key&7)
// -> every MFMA fragment is 64 consecutive 16B chunks (one coalesced dwordx4 per lane)
__global__ __launch_bounds__(256) void preconv_kernel(
        const float* __restrict__ x, u16t* __restrict__ wsK, u16t* __restrict__ wsV) {
    __shared__ __align__(16) u16t Vt[TILE_ELEMS];
    const int bid = blockIdx.x;                 // ((b*H + h)*NKT + kt)
    const int kt = bid % NKT;
    const int h  = (bid / NKT) % Hh;
    const int b  = bid / (NKT * Hh);
    const int tid = threadIdx.x;
    const float* xb = x + (size_t)b * Nn * C3 + (size_t)kt * KVBLK * C3 + 768 + h * 64;
    u16t* Kdst = wsK + (size_t)bid * TILE_ELEMS;
    u16t* Vdst = wsV + (size_t)bid * TILE_ELEMS;

    #pragma unroll
    for (int rep = 0; rep < 4; ++rep) {
        int idx = tid + rep * 256;
        int m = idx >> 4;               // key 0..63
        int d0 = (idx & 15) * 4;        // d0 in {0,4,...,60}
        const float* src = &xb[(size_t)m * C3 + d0];
        float4 k4 = *(const float4*)src;
        uint2 kp;
        kp.x = pk2a(k4.x, k4.y);
        kp.y = pk2a(k4.z, k4.w);
        int ko = (m & 31) * 8 + (m >> 5) * 256 + ((d0 >> 3) & 1) * 512
               + (d0 >> 4) * 1024 + (d0 & 7);
        *(uint2*)&Kdst[ko] = kp;        // direct global, 8B aligned
        float4 v4 = *(const float4*)(src + 768);
        int vb = ((m >> 3) & 1) * 512 + (m >> 4) * 1024 + (m & 7);
        Vt[((d0 + 0) & 31) * 8 + (((d0 + 0) >> 5) & 1) * 256 + vb] = f2b(v4.x);
        Vt[((d0 + 1) & 31) * 8 + (((d0 + 1) >> 5) & 1) * 256 + vb] = f2b(v4.y);
        Vt[((d0 + 2) & 31) * 8 + (((d0 + 2) >> 5) & 1) * 256 + vb] = f2b(v4.z);
        Vt[((d0 + 3) & 31) * 8 + (((d0 + 3) >> 5) & 1) * 256 + vb] = f2b(v4.w);
    }
    __syncthreads();
    // tile already frag-linear in LDS: plain linear copy-out
    const float4* s = (const float4*)Vt;
    float4* d = (float4*)Vdst;
    d[tid] = s[tid];
    d[tid + 256] = s[tid + 256];
}

// ---------------- pass 2: attention — 2-wave blocks, waves split KV -------------
// Block = one 32-q chunk; wave w in {0,1} = KV half (8 tiles). Grid 3072 ->
// 12 blocks/CU x 2 waves = 24 waves/CU (6/SIMD at <=85 VGPR).
// __launch_bounds__(128,3): per-wave budget 170 — the ONLY budget this body
// compiles clean at (r7: 84 VGPR). Budgets 128/102 trigger arch/acc split spill
// (r8: VGPR 48 + 876MB scratch; r9: VGPR 64 + 465MB scratch).
// LDS (12032 B): [0,7424) two 3712B wave slabs {wdiag [32][27]bf16, qrel [32][29]bf16}
//                [7424,12032) merge buffer f32 [18][64]
__global__ __launch_bounds__(128, 3) void attn_kernel(
        const float* __restrict__ x,
        const float* __restrict__ tk,
        const float* __restrict__ tv,
        const u16t* __restrict__ wsK,
        const u16t* __restrict__ wsV,
        float* __restrict__ out) {
    __shared__ __align__(16) char smem[12032];

    const int tid = threadIdx.x;
    const int work = (blockIdx.x & 7) * (NBLK / 8) + (blockIdx.x >> 3);
    const int qc = work % NQC;
    const int h  = (work / NQC) % Hh;
    const int b  = work / (NQC * Hh);
    const int lane = tid & 63;
    const int w = tid >> 6;              // kv half
    const int lq = lane & 31;
    const int hi = lane >> 5;
    const int qw0 = qc * 32;
    const int kt0 = w * 8;

    char* slab   = smem + w * 3712;
    u16t* wdiagw = (u16t*)slab;              // [32][27] bf16
    u16t* qrelw  = (u16t*)(slab + 1792);     // [32][29] bf16
    float* mb    = (float*)(smem + 7424);    // [18][64] f32

    const u16t* Kbase = wsK + (size_t)((b * Hh + h) * NKT) * TILE_ELEMS;
    const u16t* Vbase = wsV + (size_t)((b * Hh + h) * NKT) * TILE_ELEMS;
    const int lofs = lq * 8 + hi * 512;      // per-lane u16 offset inside a tile

    // ---- first-tile K/V fragments straight into registers (coalesced dwordx4) ----
    bf16x8 kfr[2][4];   // [kb][slot]
    bf16x8 vfr[4][2];   // [kbj][db]
    {
        const u16t* Kt0 = Kbase + (size_t)kt0 * TILE_ELEMS + lofs;
        const u16t* Vt0 = Vbase + (size_t)kt0 * TILE_ELEMS + lofs;
        #pragma unroll
        for (int kb = 0; kb < 2; ++kb)
            #pragma unroll
            for (int slot = 0; slot < 4; ++slot)
                kfr[kb][slot] = *(const bf16x8*)&Kt0[kb * 256 + slot * 1024];
        #pragma unroll
        for (int kbj = 0; kbj < 4; ++kbj)
            #pragma unroll
            for (int db = 0; db < 2; ++db)
                vfr[kbj][db] = *(const bf16x8*)&Vt0[db * 256 + kbj * 1024];
    }

    // ---- Q fragments direct from global, pre-scaled by KK_E ----
    const float* xq = x + (size_t)b * Nn * C3 + (size_t)(qw0 + lq) * C3 + h * 64;
    bf16x8 qB[4];
    #pragma unroll
    for (int slot = 0; slot < 4; ++slot) {
        float4 a4 = *(const float4*)&xq[slot * 16 + hi * 8];
        float4 b4 = *(const float4*)&xq[slot * 16 + hi * 8 + 4];
        union { bf16x8 v; unsigned u[4]; } pk;
        pk.u[0] = pk2a(a4.x * KK_E, a4.y * KK_E);
        pk.u[1] = pk2a(a4.z * KK_E, a4.w * KK_E);
        pk.u[2] = pk2a(b4.x * KK_E, b4.y * KK_E);
        pk.u[3] = pk2a(b4.z * KK_E, b4.w * KK_E);
        qB[slot] = pk.v;
    }

    // ---- qrel[q][t] = (KK_E*Q[q,:]).tk[t,:] via 4 MFMAs: D[q=crow(reg,hi)][t=lq] ----
    {
        const int tc = lq > 28 ? 28 : lq;
        f32x16 qr = {};
        #pragma unroll
        for (int slot = 0; slot < 4; ++slot) {
            const float* tp = &tk[tc * 64 + slot * 16 + hi * 8];
            float4 a4 = *(const float4*)tp;
            float4 b4 = *(const float4*)(tp + 4);
            union { bf16x8 v; unsigned u[4]; } pk;
            pk.u[0] = pk2a(a4.x, a4.y); pk.u[1] = pk2a(a4.z, a4.w);
            pk.u[2] = pk2a(b4.x, b4.y); pk.u[3] = pk2a(b4.z, b4.w);
            qr = __builtin_amdgcn_mfma_f32_32x32x16_bf16(qB[slot], pk.v, qr, 0, 0, 0);
        }
        if (lq <= 28) {
            #pragma unroll
            for (int reg = 0; reg < 16; ++reg) {
                int qrow = (reg & 3) + 8 * (reg >> 2) + 4 * hi;
                qrelw[qrow * NT + lq] = f2b(qr[reg]);
            }
        }
    }
    // zero wdiag (wave-private; same-wave LDS ordering)
    for (int i = lane; i < 432; i += 64) ((unsigned*)wdiagw)[i] = 0u;

    const float qb0  = b2f(qrelw[lq * NT + 0]);    // already scaled
    const float qb28 = b2f(qrelw[lq * NT + 28]);

    f32x16 of[2] = {};
    float lowA = 0.f, highA = 0.f;

    for (int kt = kt0; kt < kt0 + 8; ++kt) {
        const int key00 = kt * KVBLK;
        const bool more = (kt + 1 < kt0 + 8);
        const u16t* Ktn = Kbase + (size_t)(kt + 1) * TILE_ELEMS + lofs;
        const u16t* Vtn = Vbase + (size_t)(kt + 1) * TILE_ELEMS + lofs;

        #pragma unroll
        for (int kb = 0; kb < 2; ++kb) {
            const int kbase = key00 + kb * 32;
            const bool flo = (kbase + 31 - qw0 <= -14);
            const bool fhi = (kbase - (qw0 + 31) >= 14);
            const float binit = flo ? qb0 : (fhi ? qb28 : 0.f);
            f32x16 s;
            #pragma unroll
            for (int r = 0; r < 16; ++r) s[r] = binit;   // bias folded into C-init
            __builtin_amdgcn_s_setprio(1);
            #pragma unroll
            for (int slot = 0; slot < 4; ++slot)
                s = __builtin_amdgcn_mfma_f32_32x32x16_bf16(kfr[kb][slot], qB[slot], s, 0, 0, 0);
            __builtin_amdgcn_s_setprio(0);
            // phase-shifted reload: K(kt+1) for this kb, right after last use
            if (more) {
                #pragma unroll
                for (int slot = 0; slot < 4; ++slot)
                    kfr[kb][slot] = *(const bf16x8*)&Ktn[kb * 256 + slot * 1024];
            }
            // lane holds S^T[key = kbase+(r&3)+8*(r>>2)+4*hi][q = qw0+lq] (+bias)
            float e[16];
            if (flo || fhi) {
                #pragma unroll
                for (int r = 0; r < 16; ++r) e[r] = __builtin_amdgcn_exp2f(s[r]);
                float a0 = (e[0]+e[1]) + (e[2]+e[3]);
                float a1 = (e[4]+e[5]) + (e[6]+e[7]);
                float a2 = (e[8]+e[9]) + (e[10]+e[11]);
                float a3 = (e[12]+e[13]) + (e[14]+e[15]);
                float at = (a0+a1) + (a2+a3);
                if (flo) lowA += at; else highA += at;
            } else {
                const int qg = qw0 + lq;
                #pragma unroll
                for (int r = 0; r < 16; ++r) {
                    int key = kbase + (r & 3) + 8 * (r >> 2) + 4 * hi;
                    int delta = key - qg;
                    int t = delta + 14;
                    t = t < 0 ? 0 : (t > 28 ? 28 : t);
                    e[r] = __builtin_amdgcn_exp2f(s[r] + b2f(qrelw[lq * NT + t]));
                    if (delta <= -14)      lowA += e[r];
                    else if (delta >= 14)  highA += e[r];
                    else                   wdiagw[lq * 27 + delta + 13] = f2b(e[r]);
                }
            }
            // T12: cvt_pk + permlane32_swap -> PV B-frags in registers
            unsigned A0 = pk2a(e[0],  e[1]),  B0 = pk2a(e[2],  e[3]);
            unsigned C0 = pk2a(e[4],  e[5]),  D0 = pk2a(e[6],  e[7]);
            unsigned A1 = pk2a(e[8],  e[9]),  B1 = pk2a(e[10], e[11]);
            unsigned C1 = pk2a(e[12], e[13]), D1 = pk2a(e[14], e[15]);
            v2u r0 = __builtin_amdgcn_permlane32_swap(A0, C0, false, false);
            v2u r1 = __builtin_amdgcn_permlane32_swap(B0, D0, false, false);
            v2u r2 = __builtin_amdgcn_permlane32_swap(A1, C1, false, false);
            v2u r3 = __builtin_amdgcn_permlane32_swap(B1, D1, false, false);
            union { bf16x8 v; unsigned u[4]; } pf0, pf1;
            pf0.u[0] = r0[0]; pf0.u[1] = r1[0]; pf0.u[2] = r0[1]; pf0.u[3] = r1[1];
            pf1.u[0] = r2[0]; pf1.u[1] = r3[0]; pf1.u[2] = r2[1]; pf1.u[3] = r3[1];
            __builtin_amdgcn_s_setprio(1);
            #pragma unroll
            for (int db = 0; db < 2; ++db) {
                of[db] = __builtin_amdgcn_mfma_f32_32x32x16_bf16(vfr[kb*2+0][db], pf0.v, of[db], 0, 0, 0);
                of[db] = __builtin_amdgcn_mfma_f32_32x32x16_bf16(vfr[kb*2+1][db], pf1.v, of[db], 0, 0, 0);
            }
            __builtin_amdgcn_s_setprio(0);
            // phase-shifted reload: V(kt+1) for this kb's two key sub-groups
            if (more) {
                #pragma unroll
                for (int j = 0; j < 2; ++j)
                    #pragma unroll
                    for (int db = 0; db < 2; ++db)
                        vfr[kb*2+j][db] = *(const bf16x8*)&Vtn[db * 256 + (kb*2+j) * 1024];
            }
        }
    }

    // ---- two-phase KV-half merge (wave 1 -> wave 0) ----
    {
        if (w == 1) {
            #pragma unroll
            for (int r = 0; r < 16; ++r) mb[r * 64 + lane] = of[0][r];
            mb[16 * 64 + lane] = lowA;
            mb[17 * 64 + lane] = highA;
        }
        __syncthreads();
        if (w == 0) {
            #pragma unroll
            for (int r = 0; r < 16; ++r) of[0][r] += mb[r * 64 + lane];
            lowA  += mb[16 * 64 + lane];
            highA += mb[17 * 64 + lane];
        }
        __syncthreads();
        if (w == 1) {
            #pragma unroll
            for (int r = 0; r < 16; ++r) mb[r * 64 + lane] = of[1][r];
        }
        __syncthreads();
        if (w == 1) return;   // upper wave done; no further barriers below
        #pragma unroll
        for (int r = 0; r < 16; ++r) of[1][r] += mb[r * 64 + lane];
    }

    // ---- wave 0 only: finish sums, out2, epilogue ----
    lowA  += __shfl_xor(lowA, 32, 64);
    highA += __shfl_xor(highA, 32, 64);
    float wsum = lowA + highA;

    const u16t* wdiagup = (const u16t*)(smem + 3712);   // wave 1's slab

    float acc[2][16];
    #pragma unroll
    for (int db = 0; db < 2; ++db)
        #pragma unroll
        for (int rq = 0; rq < 4; ++rq) {
            int d0 = db * 32 + rq * 8 + hi * 4;
            float4 ta = *(const float4*)&tv[d0];
            float4 tb = *(const float4*)&tv[28 * 64 + d0];
            acc[db][rq * 4 + 0] = lowA * ta.x + highA * tb.x;
            acc[db][rq * 4 + 1] = lowA * ta.y + highA * tb.y;
            acc[db][rq * 4 + 2] = lowA * ta.z + highA * tb.z;
            acc[db][rq * 4 + 3] = lowA * ta.w + highA * tb.w;
        }
    for (int t = 1; t <= 27; ++t) {
        float wv = b2f(wdiagw[lq * 27 + t - 1]) + b2f(wdiagup[lq * 27 + t - 1]);
        wsum += wv;
        #pragma unroll
        for (int db = 0; db < 2; ++db)
            #pragma unroll
            for (int rq = 0; rq < 4; ++rq) {
                int d0 = db * 32 + rq * 8 + hi * 4;
                float4 tr = *(const float4*)&tv[t * 64 + d0];
                acc[db][rq * 4 + 0] = fmaf(wv, tr.x, acc[db][rq * 4 + 0]);
                acc[db][rq * 4 + 1] = fmaf(wv, tr.y, acc[db][rq * 4 + 1]);
                acc[db][rq * 4 + 2] = fmaf(wv, tr.z, acc[db][rq * 4 + 2]);
                acc[db][rq * 4 + 3] = fmaf(wv, tr.w, acc[db][rq * 4 + 3]);
            }
    }
    const float linv = __builtin_amdgcn_rcpf(wsum);

    {
        float* orow = &out[((size_t)b * Nn + qw0 + lq) * 768 + h * 64];
        #pragma unroll
        for (int db = 0; db < 2; ++db)
            #pragma unroll
            for (int rq = 0; rq < 4; ++rq) {
                int d0 = db * 32 + rq * 8 + hi * 4;
                float4 o4;
                o4.x = (of[db][rq * 4 + 0] + acc[db][rq * 4 + 0]) * linv;
                o4.y = (of[db][rq * 4 + 1] + acc[db][rq * 4 + 1]) * linv;
                o4.z = (of[db][rq * 4 + 2] + acc[db][rq * 4 + 2]) * linv;
                o4.w = (of[db][rq * 4 + 3] + acc[db][rq * 4 + 3]) * linv;
                *(float4*)&orow[d0] = o4;
            }
    }
}

extern "C" void kernel_launch(void* const* d_in, const int* in_sizes, int n_in,
                              void* d_out, int out_size, void* d_ws, size_t ws_size,
                              hipStream_t stream) {
    const float* x  = (const float*)d_in[0];
    const float* tk = (const float*)d_in[1];
    const float* tv = (const float*)d_in[2];
    float* out = (float*)d_out;
    u16t* wsK = (u16t*)d_ws;
    u16t* wsV = wsK + (size_t)Bb * Hh * NKT * TILE_ELEMS;
    preconv_kernel<<<dim3(Bb * Hh * NKT), dim3(256), 0, stream>>>(x, wsK, wsV);
    attn_kernel<<<dim3(NBLK), dim3(128), 0, stream>>>(x, tk, tv, wsK, wsV, out);
}